// Round 5
// baseline (4599.143 us; speedup 1.0000x reference)
//
#include <hip/hip_runtime.h>
#include <math.h>

#define K_DIM 512
#define N_DIM 512
#define NLEAF 2048   // numpy pairwise leaves of 128 over 2^18 elements
#define BM 128
#define BN 128
#define BK 32

// ws float layout: [0]=mu, [1]=gamma, [16..]=leaf sums, [2064..]=leaf abs-sums
#define WS_LEAFS 16
#define WS_LEAFA (16 + NLEAF)

// ---------------------------------------------------------------------------
// NUMERICS CONTRACT (validated rounds 3/4, absmax==0.0 — DO NOT CHANGE):
//  mu/gamma: numpy fp32 pairwise tree — 2048 leaves of 128 elems, each leaf
//    via 8-accumulator pattern + combine ((r0+r1)+(r2+r3))+((r4+r5)+(r6+r7)),
//    then perfect binary tree (left+right), scale by 2^-18.
//  eff_w = fl(fl(w + fl(sign(fl(w-mu)) - w)) * gamma)
//  y: per-output single fp32 accumulator, fmaf chain, k STRICTLY ascending.
//  epilogue: yb=y+bias; cl=clip; rr=rintf(cl*7); q=rr/7; out=yb+(q-yb).
// ---------------------------------------------------------------------------

__global__ void leaf_kernel(const float* __restrict__ w, float* __restrict__ ws) {
  const int leaf = blockIdx.x * blockDim.x + threadIdx.x;  // 2048 total
  const float* p = w + leaf * 128;
  float rs[8], ra[8];
  #pragma unroll
  for (int j = 0; j < 8; ++j) { const float v = p[j]; rs[j] = v; ra[j] = fabsf(v); }
  for (int i = 8; i < 128; i += 8) {
    #pragma unroll
    for (int j = 0; j < 8; ++j) { const float v = p[i + j]; rs[j] += v; ra[j] += fabsf(v); }
  }
  ws[WS_LEAFS + leaf] = ((rs[0] + rs[1]) + (rs[2] + rs[3])) + ((rs[4] + rs[5]) + (rs[6] + rs[7]));
  ws[WS_LEAFA + leaf] = ((ra[0] + ra[1]) + (ra[2] + ra[3])) + ((ra[4] + ra[5]) + (ra[6] + ra[7]));
}

__global__ void tree_kernel(float* __restrict__ ws) {
  __shared__ float bufS[4096];
  __shared__ float bufA[4096];
  const int t = threadIdx.x;  // 256 threads, 1 block
  for (int i = t; i < NLEAF; i += 256) {
    bufS[i] = ws[WS_LEAFS + i];
    bufA[i] = ws[WS_LEAFA + i];
  }
  __syncthreads();
  int src = 0, n = NLEAF;
  while (n > 1) {
    const int dst = src + n;
    n >>= 1;
    for (int i = t; i < n; i += 256) {
      bufS[dst + i] = bufS[src + 2 * i] + bufS[src + 2 * i + 1];
      bufA[dst + i] = bufA[src + 2 * i] + bufA[src + 2 * i + 1];
    }
    __syncthreads();
    src = dst;
  }
  if (t == 0) {
    ws[0] = bufS[src] * (1.0f / 262144.0f);
    ws[1] = bufA[src] * (1.0f / 262144.0f);
  }
}

// 128x128 tile, 256 threads, 8x8 micro-tile.
// A: read DIRECTLY from global (16-lane broadcast per address, L1-served,
//    no LDS round-trip). B: double-buffered LDS chunks (BK=32) with register
//    prefetch of the next W chunk -> ONE barrier per chunk; global-load
//    latency hidden behind the 2048-FMA chunk body.
__global__ __launch_bounds__(256, 4) void gemm_kernel(
    const float* __restrict__ x, const float* __restrict__ w,
    const float* __restrict__ bias, const float* __restrict__ ws,
    float* __restrict__ out) {
  __shared__ float Bs[2][BK][BN + 4];  // 2 x 32 x 132 x 4B = 33792 B

  const float mu = ws[0];
  const float gamma = ws[1];
  const int t = threadIdx.x;
  const int tx = t & 15;   // col group
  const int ty = t >> 4;   // row group
  const int rowBase = blockIdx.x * BM;
  const int colBase = blockIdx.y * BN;

  // B staging mapping: 4 float4 per thread per chunk
  const int bk = t >> 5;          // k rows bk, bk+8, bk+16, bk+24
  const int bn = (t & 31) * 4;    // 0..124

  // A row bases (8 rows per thread; 16 lanes share each address -> broadcast)
  const float* xr0 = x + (size_t)(rowBase + ty * 4) * K_DIM;
  const float* xr1 = xr0 + (size_t)64 * K_DIM;

  float acc[2][2][4][4];
  #pragma unroll
  for (int h = 0; h < 2; ++h)
    #pragma unroll
    for (int g = 0; g < 2; ++g)
      #pragma unroll
      for (int i = 0; i < 4; ++i)
        #pragma unroll
        for (int j = 0; j < 4; ++j) acc[h][g][i][j] = 0.0f;

  // ---- prologue: stage W chunk 0 through the faithful fp32 STE DAG
  {
    #pragma unroll
    for (int p = 0; p < 4; ++p) {
      const float4 v = *(const float4*)&w[(size_t)(bk + 8 * p) * N_DIM + colBase + bn];
      float4 e;
      const float* vi = &v.x;
      float* ei = &e.x;
      #pragma unroll
      for (int c = 0; c < 4; ++c) {
        const float wv = vi[c];
        const float wc = wv - mu;
        const float bin = (wc > 0.0f) ? 1.0f : ((wc < 0.0f) ? -1.0f : 0.0f);
        const float ste = wv + (bin - wv);   // keep exact fp32 DAG
        ei[c] = ste * gamma;
      }
      *(float4*)&Bs[0][bk + 8 * p][bn] = e;
    }
  }
  __syncthreads();

  for (int kc = 0; kc < K_DIM / BK; ++kc) {  // 16 chunks, ascending k
    const int cur = kc & 1;

    // prefetch next W chunk into registers (consumed after the compute body)
    float4 bpre[4];
    if (kc < 15) {
      #pragma unroll
      for (int p = 0; p < 4; ++p)
        bpre[p] = *(const float4*)&w[(size_t)((kc + 1) * BK + bk + 8 * p) * N_DIM + colBase + bn];
    }

    const float* bsr = &Bs[cur][0][0];  // row stride BN+4

    #pragma unroll
    for (int kg = 0; kg < BK / 2; ++kg) {  // 16 groups of 2 k
      const int kOff = kc * BK + kg * 2;
      float2 a0[4], a1[4];
      #pragma unroll
      for (int i = 0; i < 4; ++i) {
        a0[i] = *(const float2*)&xr0[(size_t)i * K_DIM + kOff];
        a1[i] = *(const float2*)&xr1[(size_t)i * K_DIM + kOff];
      }
      #pragma unroll
      for (int kk = 0; kk < 2; ++kk) {  // k ascending
        const float4 b0 = *(const float4*)&bsr[(kg * 2 + kk) * (BN + 4) + tx * 4];
        const float4 b1 = *(const float4*)&bsr[(kg * 2 + kk) * (BN + 4) + 64 + tx * 4];
        const float* b0p = &b0.x;
        const float* b1p = &b1.x;
        #pragma unroll
        for (int i = 0; i < 4; ++i) {
          const float av0 = kk ? a0[i].y : a0[i].x;
          const float av1 = kk ? a1[i].y : a1[i].x;
          #pragma unroll
          for (int j = 0; j < 4; ++j) {
            acc[0][0][i][j] = fmaf(av0, b0p[j], acc[0][0][i][j]);
            acc[0][1][i][j] = fmaf(av0, b1p[j], acc[0][1][i][j]);
            acc[1][0][i][j] = fmaf(av1, b0p[j], acc[1][0][i][j]);
            acc[1][1][i][j] = fmaf(av1, b1p[j], acc[1][1][i][j]);
          }
        }
      }
    }

    // transform + write the prefetched chunk into the other buffer
    if (kc < 15) {
      float (*bd)[BN + 4] = Bs[cur ^ 1];
      #pragma unroll
      for (int p = 0; p < 4; ++p) {
        float4 e;
        const float* vi = &bpre[p].x;
        float* ei = &e.x;
        #pragma unroll
        for (int c = 0; c < 4; ++c) {
          const float wv = vi[c];
          const float wc = wv - mu;
          const float bin = (wc > 0.0f) ? 1.0f : ((wc < 0.0f) ? -1.0f : 0.0f);
          const float ste = wv + (bin - wv);
          ei[c] = ste * gamma;
        }
        *(float4*)&bd[bk + 8 * p][bn] = e;
      }
    }
    __syncthreads();  // one barrier per chunk
  }

  // faithful fp32 epilogue (unchanged, validated)
  #pragma unroll
  for (int h = 0; h < 2; ++h)
    #pragma unroll
    for (int i = 0; i < 4; ++i) {
      const size_t row = (size_t)(rowBase + h * 64 + ty * 4 + i);
      #pragma unroll
      for (int g = 0; g < 2; ++g) {
        const int col = colBase + g * 64 + tx * 4;
        float4 o;
        float* op = &o.x;
        #pragma unroll
        for (int j = 0; j < 4; ++j) {
          const float yb = acc[h][g][i][j] + bias[col + j];
          const float cl = fminf(fmaxf(yb, -1.0f), 1.0f);
          const float t7 = cl * 7.0f;
          const float rr = rintf(t7);
          const float q = rr / 7.0f;
          op[j] = yb + (q - yb);
        }
        *(float4*)&out[row * N_DIM + col] = o;
      }
    }
}

extern "C" void kernel_launch(void* const* d_in, const int* in_sizes, int n_in,
                              void* d_out, int out_size, void* d_ws, size_t ws_size,
                              hipStream_t stream) {
  const float* x = (const float*)d_in[0];
  const float* w = (const float*)d_in[1];
  const float* bias = (const float*)d_in[2];
  float* out = (float*)d_out;
  float* ws = (float*)d_ws;  // uses 16448 bytes

  const int M = in_sizes[0] / K_DIM;  // 65536 rows

  leaf_kernel<<<NLEAF / 256, 256, 0, stream>>>(w, ws);
  tree_kernel<<<1, 256, 0, stream>>>(ws);
  gemm_kernel<<<dim3(M / BM, N_DIM / BN), 256, 0, stream>>>(x, w, bias, ws, out);
}